// Round 4
// baseline (193.643 us; speedup 1.0000x reference)
//
#include <hip/hip_runtime.h>
#include <hip/hip_bf16.h>

// ============================================================================
// ROUND 4: MEASUREMENT PROBE. Kernels are bit-identical to the R1 (126.7us)
// version except each repeats its full work REP=3 times (idempotent stores,
// per-rep pointer laundering so the compiler cannot collapse the reps).
// Purpose: push each kernel's duration past the ~45us harness fills so they
// surface in rocprof top-5 with full counters, and recover K1/K2 durations:
//   dur_us - 126.7 = 2*(K1+K2);  top-5 rows give 3*K1, 3*K2 individually.
// REVERT REP to 1 next round.
// ============================================================================
#define D 128
#define REP 3
#define GEMM_ROWS 32    // fallback tier only

typedef __bf16 bf16x8 __attribute__((ext_vector_type(8)));
typedef float  f32x4  __attribute__((ext_vector_type(4)));
typedef unsigned int u32x4 __attribute__((ext_vector_type(4)));

__device__ inline bf16x8 cvt_a8(const float* __restrict__ p) {
    float4 v0 = ((const float4*)p)[0], v1 = ((const float4*)p)[1];
    bf16x8 a;
    a[0] = (__bf16)v0.x; a[1] = (__bf16)v0.y; a[2] = (__bf16)v0.z; a[3] = (__bf16)v0.w;
    a[4] = (__bf16)v1.x; a[5] = (__bf16)v1.y; a[6] = (__bf16)v1.z; a[7] = (__bf16)v1.w;
    return a;
}

__global__ __launch_bounds__(256) void fused_gemm_rp(
        const float* __restrict__ x, const float* __restrict__ w,
        const int* __restrict__ rows,
        unsigned short* __restrict__ h, int* __restrict__ rp,
        int n_nodes, int n_edges, int gemm_blocks) {
    const int b = blockIdx.x;

    if (b >= gemm_blocks) {           // ---- row_ptr builder blocks ----
        int e = (b - gemm_blocks) * 256 + threadIdx.x;
        if (e >= n_edges) return;
#pragma unroll 1
        for (int rep = 0; rep < REP; ++rep) {
            const int* rl = rows;
            asm volatile("" : "+v"(rl));          // defeat cross-rep CSE/DSE
            int r    = rl[e];
            int prev = (e == 0) ? -1 : rl[e - 1];
            for (int rr = prev + 1; rr <= r; ++rr) rp[rr] = e;
            if (e == n_edges - 1)
                for (int rr = r + 1; rr <= n_nodes; ++rr) rp[rr] = n_edges;
        }
        return;
    }

    const int wave = threadIdx.x >> 6;
    const int lane = threadIdx.x & 63;
    const int m16  = lane & 15;
    const int q    = lane >> 4;

    const int row0 = b * 64;
    const int col0 = wave * 32;

    bf16x8 bfr[2][4];
#pragma unroll
    for (int t = 0; t < 2; ++t)
#pragma unroll
        for (int s = 0; s < 4; ++s) {
            const float* wp = w + (size_t)(32 * s + q * 8) * D + col0 + 16 * t + m16;
#pragma unroll
            for (int j = 0; j < 8; ++j)
                bfr[t][s][j] = (__bf16)wp[(size_t)j * D];
        }

#pragma unroll 1
    for (int rep = 0; rep < REP; ++rep) {
        const float* xr = x;
        asm volatile("" : "+v"(xr));              // defeat cross-rep CSE/DSE
#pragma unroll 1
        for (int sl = 0; sl < 4; ++sl) {
            const int r = row0 + sl * 16 + m16;
            const float* xp = xr + (size_t)r * D + q * 8;

            bf16x8 a[4];
            if (r < n_nodes) {
#pragma unroll
                for (int s = 0; s < 4; ++s) a[s] = cvt_a8(xp + 32 * s);
            } else {
#pragma unroll
                for (int s = 0; s < 4; ++s)
#pragma unroll
                    for (int j = 0; j < 8; ++j) a[s][j] = (__bf16)0.f;
            }

            f32x4 acc0 = (f32x4)0.f, acc1 = (f32x4)0.f;
#pragma unroll
            for (int s = 0; s < 4; ++s) {
                acc0 = __builtin_amdgcn_mfma_f32_16x16x32_bf16(a[s], bfr[0][s], acc0, 0, 0, 0);
                acc1 = __builtin_amdgcn_mfma_f32_16x16x32_bf16(a[s], bfr[1][s], acc1, 0, 0, 0);
            }

#pragma unroll
            for (int i = 0; i < 4; ++i) {
                int row = row0 + sl * 16 + q * 4 + i;
                h[(size_t)row * D + col0 + m16]      = __builtin_bit_cast(unsigned short, (__bf16)acc0[i]);
                h[(size_t)row * D + col0 + 16 + m16] = __builtin_bit_cast(unsigned short, (__bf16)acc1[i]);
            }
        }
    }
}

// ---------------------------------------------------------------------------
// K2: SpMM, R1 structure (4 chains x 16 lanes x 16B, batch-4 gathers),
// wrapped in REP loop for measurement.
// ---------------------------------------------------------------------------
#define FMA8(hv, vv)                                                              \
    _Pragma("unroll")                                                             \
    for (int j = 0; j < 4; ++j) {                                                 \
        unsigned int u = (hv)[j];                                                 \
        acc[2 * j]     = fmaf((vv), __builtin_bit_cast(float, u << 16),           \
                              acc[2 * j]);                                        \
        acc[2 * j + 1] = fmaf((vv), __builtin_bit_cast(float, u & 0xFFFF0000u),   \
                              acc[2 * j + 1]);                                    \
    }

__global__ __launch_bounds__(256) void spmm_bf16_b4(
        const unsigned short* __restrict__ h,
        const int* __restrict__ row_ptr,
        const int* __restrict__ cols,
        const float* __restrict__ vals,
        float* __restrict__ out, int n) {
    const int wave = threadIdx.x >> 6;
    const int lane = threadIdx.x & 63;
    const int r = blockIdx.x * 4 + wave;
    if (r >= n) return;

    const int start = row_ptr[r];
    const int end   = row_ptr[r + 1];
    const int chain = lane >> 4;
    const int l4    = lane & 15;

#pragma unroll 1
    for (int rep = 0; rep < REP; ++rep) {
        const u32x4* h4 = (const u32x4*)h;
        const int*   cl = cols;
        const float* vl = vals;
        asm volatile("" : "+v"(h4), "+v"(cl), "+v"(vl));   // defeat rep collapse

        float acc[8];
#pragma unroll
        for (int j = 0; j < 8; ++j) acc[j] = 0.f;

        int e = start + chain;
        int c0 = 0, c1 = 0, c2 = 0, c3 = 0;
        float v0 = 0.f, v1 = 0.f, v2 = 0.f, v3 = 0.f;
        if (e < end)      { c0 = cl[e];      v0 = vl[e]; }
        if (e + 4 < end)  { c1 = cl[e + 4];  v1 = vl[e + 4]; }
        if (e + 8 < end)  { c2 = cl[e + 8];  v2 = vl[e + 8]; }
        if (e + 12 < end) { c3 = cl[e + 12]; v3 = vl[e + 12]; }

        while (e < end) {
            int en = e + 16;
            int cn0 = 0, cn1 = 0, cn2 = 0, cn3 = 0;
            float vn0 = 0.f, vn1 = 0.f, vn2 = 0.f, vn3 = 0.f;
            if (en < end)      { cn0 = cl[en];      vn0 = vl[en]; }
            if (en + 4 < end)  { cn1 = cl[en + 4];  vn1 = vl[en + 4]; }
            if (en + 8 < end)  { cn2 = cl[en + 8];  vn2 = vl[en + 8]; }
            if (en + 12 < end) { cn3 = cl[en + 12]; vn3 = vl[en + 12]; }

            u32x4 hv0 = h4[(size_t)c0 * (D / 8) + l4];
            u32x4 hv1 = h4[(size_t)c1 * (D / 8) + l4];
            u32x4 hv2 = h4[(size_t)c2 * (D / 8) + l4];
            u32x4 hv3 = h4[(size_t)c3 * (D / 8) + l4];

            FMA8(hv0, v0)
            FMA8(hv1, v1)
            FMA8(hv2, v2)
            FMA8(hv3, v3)

            c0 = cn0; v0 = vn0; c1 = cn1; v1 = vn1;
            c2 = cn2; v2 = vn2; c3 = cn3; v3 = vn3;
            e = en;
        }

#pragma unroll
        for (int j = 0; j < 8; ++j) {
            acc[j] += __shfl_xor(acc[j], 16);
            acc[j] += __shfl_xor(acc[j], 32);
        }

        if (chain == 0) {
            float4 o0, o1;
            o0.x = fmaxf(acc[0], 0.f); o0.y = fmaxf(acc[1], 0.f);
            o0.z = fmaxf(acc[2], 0.f); o0.w = fmaxf(acc[3], 0.f);
            o1.x = fmaxf(acc[4], 0.f); o1.y = fmaxf(acc[5], 0.f);
            o1.z = fmaxf(acc[6], 0.f); o1.w = fmaxf(acc[7], 0.f);
            float4* op = (float4*)(out + (size_t)r * D + l4 * 8);
            op[0] = o0; op[1] = o1;
        }
    }
}

// ============================ fallback tiers ===============================
__global__ __launch_bounds__(256) void gemm128(const float* __restrict__ x,
                                               const float* __restrict__ w,
                                               float* __restrict__ h, int n) {
    __shared__ float4 ws4[D * D / 4];
    __shared__ float  xs[GEMM_ROWS][D];
    const int tid  = threadIdx.x;
    const int row0 = blockIdx.x * GEMM_ROWS;
    const float4* w4 = (const float4*)w;
    for (int i = tid; i < D * D / 4; i += 256) ws4[i] = w4[i];
    float4* xs4 = (float4*)&xs[0][0];
    const float4* x4 = (const float4*)x;
    for (int i = tid; i < GEMM_ROWS * D / 4; i += 256) {
        int row = row0 + (i >> 5);
        float4 v = make_float4(0.f, 0.f, 0.f, 0.f);
        if (row < n) v = x4[(size_t)row0 * (D / 4) + i];
        xs4[i] = v;
    }
    __syncthreads();
    const int tx = tid & 31, ty = tid >> 5;
    float4 acc[4];
#pragma unroll
    for (int i = 0; i < 4; ++i) acc[i] = make_float4(0.f, 0.f, 0.f, 0.f);
#pragma unroll 8
    for (int k = 0; k < D; ++k) {
        float4 wv = ws4[k * (D / 4) + tx];
#pragma unroll
        for (int i = 0; i < 4; ++i) {
            float xv = xs[ty * 4 + i][k];
            acc[i].x = fmaf(xv, wv.x, acc[i].x);
            acc[i].y = fmaf(xv, wv.y, acc[i].y);
            acc[i].z = fmaf(xv, wv.z, acc[i].z);
            acc[i].w = fmaf(xv, wv.w, acc[i].w);
        }
    }
#pragma unroll
    for (int i = 0; i < 4; ++i) {
        int row = row0 + ty * 4 + i;
        if (row < n) ((float4*)(h + (size_t)row * D))[tx] = acc[i];
    }
}

__global__ __launch_bounds__(128) void spmm_row(const float* __restrict__ h,
                                                const int* __restrict__ rows,
                                                const int* __restrict__ cols,
                                                const float* __restrict__ vals,
                                                float* __restrict__ out, int n_edges) {
    const int r = blockIdx.x, d = threadIdx.x;
    int lo = 0, hi = n_edges;
    while (lo < hi) { int m = (lo + hi) >> 1; if (rows[m] < r) lo = m + 1; else hi = m; }
    const int start = lo;
    hi = n_edges;
    while (lo < hi) { int m = (lo + hi) >> 1; if (rows[m] <= r) lo = m + 1; else hi = m; }
    const int end = lo;
    float acc = 0.f;
    for (int e = start; e < end; ++e)
        acc = fmaf(vals[e], h[(size_t)cols[e] * D + d], acc);
    out[(size_t)r * D + d] = fmaxf(acc, 0.f);
}

__global__ __launch_bounds__(128) void fused_fallback(
        const float* __restrict__ x, const float* __restrict__ w,
        const int* __restrict__ rows, const int* __restrict__ cols,
        const float* __restrict__ vals, float* __restrict__ out, int n_edges) {
    const int r = blockIdx.x, d = threadIdx.x;
    int lo = 0, hi = n_edges;
    while (lo < hi) { int m = (lo + hi) >> 1; if (rows[m] < r) lo = m + 1; else hi = m; }
    const int start = lo;
    hi = n_edges;
    while (lo < hi) { int m = (lo + hi) >> 1; if (rows[m] <= r) lo = m + 1; else hi = m; }
    const int end = lo;
    float acc = 0.f;
    for (int e = start; e < end; ++e) {
        int c = cols[e]; float v = vals[e];
        float hcd = 0.f;
        for (int k = 0; k < D; ++k)
            hcd = fmaf(x[(size_t)c * D + k], w[(size_t)k * D + d], hcd);
        acc = fmaf(v, hcd, acc);
    }
    out[(size_t)r * D + d] = fmaxf(acc, 0.f);
}

// ===========================================================================
extern "C" void kernel_launch(void* const* d_in, const int* in_sizes, int n_in,
                              void* d_out, int out_size, void* d_ws, size_t ws_size,
                              hipStream_t stream) {
    const float* x    = (const float*)d_in[0];
    const float* w    = (const float*)d_in[1];
    const int*   rows = (const int*)d_in[2];
    const int*   cols = (const int*)d_in[3];
    const float* vals = (const float*)d_in[4];
    float* out = (float*)d_out;

    const int n_nodes = in_sizes[0] / D;              // 50000
    const int n_edges = in_sizes[2];                  // 800000
    const int n_pad   = (n_nodes + 63) & ~63;         // 50048

    const size_t h_bytes  = (size_t)n_pad * D * sizeof(unsigned short);  // 12.8 MB
    const size_t rp_off   = h_bytes;
    const size_t need     = rp_off + (size_t)(n_nodes + 1) * sizeof(int);
    const size_t hf_bytes = (size_t)n_nodes * D * sizeof(float);

    if (ws_size >= need) {
        unsigned short* h  = (unsigned short*)d_ws;
        int*            rp = (int*)((char*)d_ws + rp_off);

        const int gemm_blocks = n_pad / 64;                      // 782
        const int rp_blocks   = (n_edges + 255) / 256;           // 3125
        fused_gemm_rp<<<gemm_blocks + rp_blocks, 256, 0, stream>>>(
            x, w, rows, h, rp, n_nodes, n_edges, gemm_blocks);

        spmm_bf16_b4<<<(n_nodes + 3) / 4, 256, 0, stream>>>(h, rp, cols, vals, out, n_nodes);
    } else if (ws_size >= hf_bytes) {
        float* hf = (float*)d_ws;
        gemm128<<<(n_nodes + GEMM_ROWS - 1) / GEMM_ROWS, 256, 0, stream>>>(x, w, hf, n_nodes);
        spmm_row<<<n_nodes, 128, 0, stream>>>(hf, rows, cols, vals, out, n_edges);
    } else {
        fused_fallback<<<n_nodes, 128, 0, stream>>>(x, w, rows, cols, vals, out, n_edges);
    }
}

// Round 5
// 153.656 us; speedup vs baseline: 1.2602x; 1.2602x over previous
//
#include <hip/hip_runtime.h>
#include <hip/hip_bf16.h>

// ============================================================================
// R5: h stored as F32 (was bf16). R4 probe showed K2 is VALU-issue-bound
// (VALUBusy 70%, hbm 25%, MfmaUtil 0): the bf16 unpack (shl+and per 2 elems)
// doubled VALU ops on the critical pipe to save HBM bytes we didn't need.
// f32 h: per edge-lane 2x dwordx4 loads + 2x v4f32 fma (lowerable to
// v_pk_fma_f32). K1 writes f32 h directly (+12.8MB stream, ~+2us).
// Measured split (R4 REP=3 probe): K1 ~10.3us, K2 ~23.2us, fills ~90us fixed.
// ============================================================================
#define D 128
#define GEMM_ROWS 32    // fallback tier only

typedef __bf16 bf16x8 __attribute__((ext_vector_type(8)));
typedef float  f32x4  __attribute__((ext_vector_type(4)));

__device__ inline bf16x8 cvt_a8(const float* __restrict__ p) {
    float4 v0 = ((const float4*)p)[0], v1 = ((const float4*)p)[1];
    bf16x8 a;
    a[0] = (__bf16)v0.x; a[1] = (__bf16)v0.y; a[2] = (__bf16)v0.z; a[3] = (__bf16)v0.w;
    a[4] = (__bf16)v1.x; a[5] = (__bf16)v1.y; a[6] = (__bf16)v1.z; a[7] = (__bf16)v1.w;
    return a;
}

// ---------------------------------------------------------------------------
// K1: fused GEMM + row_ptr (R1 structure; h stores are now f32).
// ---------------------------------------------------------------------------
__global__ __launch_bounds__(256) void fused_gemm_rp(
        const float* __restrict__ x, const float* __restrict__ w,
        const int* __restrict__ rows,
        float* __restrict__ h, int* __restrict__ rp,
        int n_nodes, int n_edges, int gemm_blocks) {
    const int b = blockIdx.x;

    if (b >= gemm_blocks) {           // ---- row_ptr builder blocks ----
        int e = (b - gemm_blocks) * 256 + threadIdx.x;
        if (e >= n_edges) return;
        int r    = rows[e];
        int prev = (e == 0) ? -1 : rows[e - 1];
        for (int rr = prev + 1; rr <= r; ++rr) rp[rr] = e;
        if (e == n_edges - 1)
            for (int rr = r + 1; rr <= n_nodes; ++rr) rp[rr] = n_edges;
        return;
    }

    const int wave = threadIdx.x >> 6;
    const int lane = threadIdx.x & 63;
    const int m16  = lane & 15;
    const int q    = lane >> 4;

    const int row0 = b * 64;
    const int col0 = wave * 32;

    bf16x8 bfr[2][4];
#pragma unroll
    for (int t = 0; t < 2; ++t)
#pragma unroll
        for (int s = 0; s < 4; ++s) {
            const float* wp = w + (size_t)(32 * s + q * 8) * D + col0 + 16 * t + m16;
#pragma unroll
            for (int j = 0; j < 8; ++j)
                bfr[t][s][j] = (__bf16)wp[(size_t)j * D];
        }

#pragma unroll 1
    for (int sl = 0; sl < 4; ++sl) {
        const int r = row0 + sl * 16 + m16;
        const float* xp = x + (size_t)r * D + q * 8;

        bf16x8 a[4];
        if (r < n_nodes) {
#pragma unroll
            for (int s = 0; s < 4; ++s) a[s] = cvt_a8(xp + 32 * s);
        } else {
#pragma unroll
            for (int s = 0; s < 4; ++s)
#pragma unroll
                for (int j = 0; j < 8; ++j) a[s][j] = (__bf16)0.f;
        }

        f32x4 acc0 = (f32x4)0.f, acc1 = (f32x4)0.f;
#pragma unroll
        for (int s = 0; s < 4; ++s) {
            acc0 = __builtin_amdgcn_mfma_f32_16x16x32_bf16(a[s], bfr[0][s], acc0, 0, 0, 0);
            acc1 = __builtin_amdgcn_mfma_f32_16x16x32_bf16(a[s], bfr[1][s], acc1, 0, 0, 0);
        }

#pragma unroll
        for (int i = 0; i < 4; ++i) {
            int row = row0 + sl * 16 + q * 4 + i;
            h[(size_t)row * D + col0 + m16]      = acc0[i];
            h[(size_t)row * D + col0 + 16 + m16] = acc1[i];
        }
    }
}

// ---------------------------------------------------------------------------
// K2: SpMM on f32 h — 4 chains x 16 lanes, batch-4 gathers (8 dwordx4 loads
// in flight per wave), inner product = pure v4f32 FMA, no unpack.
// ---------------------------------------------------------------------------
__global__ __launch_bounds__(256) void spmm_f32_b4(
        const float* __restrict__ h,
        const int* __restrict__ row_ptr,
        const int* __restrict__ cols,
        const float* __restrict__ vals,
        float* __restrict__ out, int n) {
    const int wave = threadIdx.x >> 6;
    const int lane = threadIdx.x & 63;
    const int r = blockIdx.x * 4 + wave;
    if (r >= n) return;

    const int start = row_ptr[r];
    const int end   = row_ptr[r + 1];
    const int chain = lane >> 4;    // 4 edge chains, stride 4
    const int l4    = lane & 15;    // 32B slot: dims [l4*8, l4*8+8)

    const f32x4* h4 = (const f32x4*)h;     // D/4 = 32 f32x4 per row
    f32x4 accA = (f32x4)0.f, accB = (f32x4)0.f;

    int e = start + chain;
    int c0 = 0, c1 = 0, c2 = 0, c3 = 0;
    float v0 = 0.f, v1 = 0.f, v2 = 0.f, v3 = 0.f;
    if (e < end)      { c0 = cols[e];      v0 = vals[e]; }
    if (e + 4 < end)  { c1 = cols[e + 4];  v1 = vals[e + 4]; }
    if (e + 8 < end)  { c2 = cols[e + 8];  v2 = vals[e + 8]; }
    if (e + 12 < end) { c3 = cols[e + 12]; v3 = vals[e + 12]; }

    while (e < end) {
        // prefetch next batch's indices (overlaps the gathers below)
        int en = e + 16;
        int cn0 = 0, cn1 = 0, cn2 = 0, cn3 = 0;
        float vn0 = 0.f, vn1 = 0.f, vn2 = 0.f, vn3 = 0.f;
        if (en < end)      { cn0 = cols[en];      vn0 = vals[en]; }
        if (en + 4 < end)  { cn1 = cols[en + 4];  vn1 = vals[en + 4]; }
        if (en + 8 < end)  { cn2 = cols[en + 8];  vn2 = vals[en + 8]; }
        if (en + 12 < end) { cn3 = cols[en + 12]; vn3 = vals[en + 12]; }

        // all eight 16B gathers in flight before any is consumed
        const size_t b0 = (size_t)c0 * (D / 4) + l4 * 2;
        const size_t b1 = (size_t)c1 * (D / 4) + l4 * 2;
        const size_t b2 = (size_t)c2 * (D / 4) + l4 * 2;
        const size_t b3 = (size_t)c3 * (D / 4) + l4 * 2;
        f32x4 lo0 = h4[b0], hi0 = h4[b0 + 1];
        f32x4 lo1 = h4[b1], hi1 = h4[b1 + 1];
        f32x4 lo2 = h4[b2], hi2 = h4[b2 + 1];
        f32x4 lo3 = h4[b3], hi3 = h4[b3 + 1];

        accA = __builtin_elementwise_fma((f32x4)v0, lo0, accA);
        accB = __builtin_elementwise_fma((f32x4)v0, hi0, accB);
        accA = __builtin_elementwise_fma((f32x4)v1, lo1, accA);
        accB = __builtin_elementwise_fma((f32x4)v1, hi1, accB);
        accA = __builtin_elementwise_fma((f32x4)v2, lo2, accA);
        accB = __builtin_elementwise_fma((f32x4)v2, hi2, accB);
        accA = __builtin_elementwise_fma((f32x4)v3, lo3, accA);
        accB = __builtin_elementwise_fma((f32x4)v3, hi3, accB);

        c0 = cn0; v0 = vn0; c1 = cn1; v1 = vn1;
        c2 = cn2; v2 = vn2; c3 = cn3; v3 = vn3;
        e = en;
    }

    // combine 4 chains (chain index in lane bits 4,5)
#pragma unroll
    for (int j = 0; j < 4; ++j) {
        accA[j] += __shfl_xor(accA[j], 16);
        accA[j] += __shfl_xor(accA[j], 32);
        accB[j] += __shfl_xor(accB[j], 16);
        accB[j] += __shfl_xor(accB[j], 32);
    }

    if (chain == 0) {
        float4 o0, o1;
        o0.x = fmaxf(accA[0], 0.f); o0.y = fmaxf(accA[1], 0.f);
        o0.z = fmaxf(accA[2], 0.f); o0.w = fmaxf(accA[3], 0.f);
        o1.x = fmaxf(accB[0], 0.f); o1.y = fmaxf(accB[1], 0.f);
        o1.z = fmaxf(accB[2], 0.f); o1.w = fmaxf(accB[3], 0.f);
        float4* op = (float4*)(out + (size_t)r * D + l4 * 8);
        op[0] = o0; op[1] = o1;
    }
}

// ============================ fallback tiers ===============================
__global__ __launch_bounds__(256) void gemm128(const float* __restrict__ x,
                                               const float* __restrict__ w,
                                               float* __restrict__ h, int n) {
    __shared__ float4 ws4[D * D / 4];
    __shared__ float  xs[GEMM_ROWS][D];
    const int tid  = threadIdx.x;
    const int row0 = blockIdx.x * GEMM_ROWS;
    const float4* w4 = (const float4*)w;
    for (int i = tid; i < D * D / 4; i += 256) ws4[i] = w4[i];
    float4* xs4 = (float4*)&xs[0][0];
    const float4* x4 = (const float4*)x;
    for (int i = tid; i < GEMM_ROWS * D / 4; i += 256) {
        int row = row0 + (i >> 5);
        float4 v = make_float4(0.f, 0.f, 0.f, 0.f);
        if (row < n) v = x4[(size_t)row0 * (D / 4) + i];
        xs4[i] = v;
    }
    __syncthreads();
    const int tx = tid & 31, ty = tid >> 5;
    float4 acc[4];
#pragma unroll
    for (int i = 0; i < 4; ++i) acc[i] = make_float4(0.f, 0.f, 0.f, 0.f);
#pragma unroll 8
    for (int k = 0; k < D; ++k) {
        float4 wv = ws4[k * (D / 4) + tx];
#pragma unroll
        for (int i = 0; i < 4; ++i) {
            float xv = xs[ty * 4 + i][k];
            acc[i].x = fmaf(xv, wv.x, acc[i].x);
            acc[i].y = fmaf(xv, wv.y, acc[i].y);
            acc[i].z = fmaf(xv, wv.z, acc[i].z);
            acc[i].w = fmaf(xv, wv.w, acc[i].w);
        }
    }
#pragma unroll
    for (int i = 0; i < 4; ++i) {
        int row = row0 + ty * 4 + i;
        if (row < n) ((float4*)(h + (size_t)row * D))[tx] = acc[i];
    }
}

__global__ __launch_bounds__(128) void spmm_row(const float* __restrict__ h,
                                                const int* __restrict__ rows,
                                                const int* __restrict__ cols,
                                                const float* __restrict__ vals,
                                                float* __restrict__ out, int n_edges) {
    const int r = blockIdx.x, d = threadIdx.x;
    int lo = 0, hi = n_edges;
    while (lo < hi) { int m = (lo + hi) >> 1; if (rows[m] < r) lo = m + 1; else hi = m; }
    const int start = lo;
    hi = n_edges;
    while (lo < hi) { int m = (lo + hi) >> 1; if (rows[m] <= r) lo = m + 1; else hi = m; }
    const int end = lo;
    float acc = 0.f;
    for (int e = start; e < end; ++e)
        acc = fmaf(vals[e], h[(size_t)cols[e] * D + d], acc);
    out[(size_t)r * D + d] = fmaxf(acc, 0.f);
}

__global__ __launch_bounds__(128) void fused_fallback(
        const float* __restrict__ x, const float* __restrict__ w,
        const int* __restrict__ rows, const int* __restrict__ cols,
        const float* __restrict__ vals, float* __restrict__ out, int n_edges) {
    const int r = blockIdx.x, d = threadIdx.x;
    int lo = 0, hi = n_edges;
    while (lo < hi) { int m = (lo + hi) >> 1; if (rows[m] < r) lo = m + 1; else hi = m; }
    const int start = lo;
    hi = n_edges;
    while (lo < hi) { int m = (lo + hi) >> 1; if (rows[m] <= r) lo = m + 1; else hi = m; }
    const int end = lo;
    float acc = 0.f;
    for (int e = start; e < end; ++e) {
        int c = cols[e]; float v = vals[e];
        float hcd = 0.f;
        for (int k = 0; k < D; ++k)
            hcd = fmaf(x[(size_t)c * D + k], w[(size_t)k * D + d], hcd);
        acc = fmaf(v, hcd, acc);
    }
    out[(size_t)r * D + d] = fmaxf(acc, 0.f);
}

// ===========================================================================
extern "C" void kernel_launch(void* const* d_in, const int* in_sizes, int n_in,
                              void* d_out, int out_size, void* d_ws, size_t ws_size,
                              hipStream_t stream) {
    const float* x    = (const float*)d_in[0];
    const float* w    = (const float*)d_in[1];
    const int*   rows = (const int*)d_in[2];
    const int*   cols = (const int*)d_in[3];
    const float* vals = (const float*)d_in[4];
    float* out = (float*)d_out;

    const int n_nodes = in_sizes[0] / D;              // 50000
    const int n_edges = in_sizes[2];                  // 800000
    const int n_pad   = (n_nodes + 63) & ~63;         // 50048

    const size_t h_bytes  = (size_t)n_pad * D * sizeof(float);           // 25.6 MB
    const size_t rp_off   = h_bytes;
    const size_t need     = rp_off + (size_t)(n_nodes + 1) * sizeof(int);
    const size_t hf_bytes = (size_t)n_nodes * D * sizeof(float);

    if (ws_size >= need) {
        float* h  = (float*)d_ws;
        int*   rp = (int*)((char*)d_ws + rp_off);

        const int gemm_blocks = n_pad / 64;                      // 782
        const int rp_blocks   = (n_edges + 255) / 256;           // 3125
        fused_gemm_rp<<<gemm_blocks + rp_blocks, 256, 0, stream>>>(
            x, w, rows, h, rp, n_nodes, n_edges, gemm_blocks);

        spmm_f32_b4<<<(n_nodes + 3) / 4, 256, 0, stream>>>(h, rp, cols, vals, out, n_nodes);
    } else if (ws_size >= hf_bytes) {
        float* hf = (float*)d_ws;
        gemm128<<<(n_nodes + GEMM_ROWS - 1) / GEMM_ROWS, 256, 0, stream>>>(x, w, hf, n_nodes);
        spmm_row<<<n_nodes, 128, 0, stream>>>(hf, rows, cols, vals, out, n_edges);
    } else {
        fused_fallback<<<n_nodes, 128, 0, stream>>>(x, w, rows, cols, vals, out, n_edges);
    }
}

// Round 6
// 127.033 us; speedup vs baseline: 1.5244x; 1.2096x over previous
//
#include <hip/hip_runtime.h>
#include <hip/hip_bf16.h>

// ============================================================================
// R6: bf16 h REVERT (R5's f32 h doubled the gather footprint: FETCH 29->181MB,
// K2 23->54us -- bf16's 12.8MB table is the cache-friendly choice) + K2 VALU
// diet at constant memory pattern:
//   - float2 unpack + __builtin_elementwise_fma -> v_pk_fma_f32 (3 VALU/u32
//     instead of 4)
//   - no cross-batch index prefetch (R1 showed extra MLP is free of benefit;
//     clamped in-batch loads cost ~15 ops vs ~40)
// Measured so far: fills ~90us fixed, K1 ~10us, K2(bf16,R1) ~23us balanced
// between VALU issue (~16us) and cache service (~20us).
// ============================================================================
#define D 128
#define GEMM_ROWS 32    // fallback tier only

typedef __bf16 bf16x8 __attribute__((ext_vector_type(8)));
typedef float  f32x4  __attribute__((ext_vector_type(4)));
typedef float  f32x2  __attribute__((ext_vector_type(2)));
typedef unsigned int u32x4 __attribute__((ext_vector_type(4)));

__device__ inline bf16x8 cvt_a8(const float* __restrict__ p) {
    float4 v0 = ((const float4*)p)[0], v1 = ((const float4*)p)[1];
    bf16x8 a;
    a[0] = (__bf16)v0.x; a[1] = (__bf16)v0.y; a[2] = (__bf16)v0.z; a[3] = (__bf16)v0.w;
    a[4] = (__bf16)v1.x; a[5] = (__bf16)v1.y; a[6] = (__bf16)v1.z; a[7] = (__bf16)v1.w;
    return a;
}

// ---------------------------------------------------------------------------
// K1: fused GEMM + row_ptr (identical to the verified R1 kernel; bf16 h).
// ---------------------------------------------------------------------------
__global__ __launch_bounds__(256) void fused_gemm_rp(
        const float* __restrict__ x, const float* __restrict__ w,
        const int* __restrict__ rows,
        unsigned short* __restrict__ h, int* __restrict__ rp,
        int n_nodes, int n_edges, int gemm_blocks) {
    const int b = blockIdx.x;

    if (b >= gemm_blocks) {           // ---- row_ptr builder blocks ----
        int e = (b - gemm_blocks) * 256 + threadIdx.x;
        if (e >= n_edges) return;
        int r    = rows[e];
        int prev = (e == 0) ? -1 : rows[e - 1];
        for (int rr = prev + 1; rr <= r; ++rr) rp[rr] = e;
        if (e == n_edges - 1)
            for (int rr = r + 1; rr <= n_nodes; ++rr) rp[rr] = n_edges;
        return;
    }

    const int wave = threadIdx.x >> 6;
    const int lane = threadIdx.x & 63;
    const int m16  = lane & 15;
    const int q    = lane >> 4;

    const int row0 = b * 64;
    const int col0 = wave * 32;

    bf16x8 bfr[2][4];
#pragma unroll
    for (int t = 0; t < 2; ++t)
#pragma unroll
        for (int s = 0; s < 4; ++s) {
            const float* wp = w + (size_t)(32 * s + q * 8) * D + col0 + 16 * t + m16;
#pragma unroll
            for (int j = 0; j < 8; ++j)
                bfr[t][s][j] = (__bf16)wp[(size_t)j * D];
        }

#pragma unroll 1
    for (int sl = 0; sl < 4; ++sl) {
        const int r = row0 + sl * 16 + m16;
        const float* xp = x + (size_t)r * D + q * 8;

        bf16x8 a[4];
        if (r < n_nodes) {
#pragma unroll
            for (int s = 0; s < 4; ++s) a[s] = cvt_a8(xp + 32 * s);
        } else {
#pragma unroll
            for (int s = 0; s < 4; ++s)
#pragma unroll
                for (int j = 0; j < 8; ++j) a[s][j] = (__bf16)0.f;
        }

        f32x4 acc0 = (f32x4)0.f, acc1 = (f32x4)0.f;
#pragma unroll
        for (int s = 0; s < 4; ++s) {
            acc0 = __builtin_amdgcn_mfma_f32_16x16x32_bf16(a[s], bfr[0][s], acc0, 0, 0, 0);
            acc1 = __builtin_amdgcn_mfma_f32_16x16x32_bf16(a[s], bfr[1][s], acc1, 0, 0, 0);
        }

#pragma unroll
        for (int i = 0; i < 4; ++i) {
            int row = row0 + sl * 16 + q * 4 + i;
            h[(size_t)row * D + col0 + m16]      = __builtin_bit_cast(unsigned short, (__bf16)acc0[i]);
            h[(size_t)row * D + col0 + 16 + m16] = __builtin_bit_cast(unsigned short, (__bf16)acc1[i]);
        }
    }
}

// ---------------------------------------------------------------------------
// K2: SpMM on bf16 h. 4 chains x 16 lanes x 16B, batch-4 gathers (memory
// pattern identical to R1/R4). VALU diet: float2+pk_fma unpack, clamped
// in-batch index loads, no cross-batch prefetch.
// ---------------------------------------------------------------------------
#define PKFMA(hv, vv)                                                          \
    _Pragma("unroll")                                                          \
    for (int j = 0; j < 4; ++j) {                                              \
        unsigned int u = (hv)[j];                                              \
        f32x2 f;                                                               \
        f[0] = __builtin_bit_cast(float, u << 16);                             \
        f[1] = __builtin_bit_cast(float, u & 0xFFFF0000u);                     \
        acc2[j] = __builtin_elementwise_fma((f32x2)(vv), f, acc2[j]);          \
    }

__global__ __launch_bounds__(256) void spmm_bf16_pk(
        const unsigned short* __restrict__ h,
        const int* __restrict__ row_ptr,
        const int* __restrict__ cols,
        const float* __restrict__ vals,
        float* __restrict__ out, int n) {
    const int wave = threadIdx.x >> 6;
    const int lane = threadIdx.x & 63;
    const int r = blockIdx.x * 4 + wave;
    if (r >= n) return;

    const int start = row_ptr[r];
    const int end   = row_ptr[r + 1];
    const int chain = lane >> 4;    // 4 edge chains, stride 4
    const int l4    = lane & 15;    // 16B slot: dims [l4*8, l4*8+8)

    const u32x4* h4 = (const u32x4*)h;
    f32x2 acc2[4];
#pragma unroll
    for (int j = 0; j < 4; ++j) acc2[j] = (f32x2)0.f;

    const int last = end - 1;
    int e = start + chain;
    while (e < end) {
        // clamped index loads (1 load + 1 select each for v1..v3)
        int i1 = (e + 4  <= last) ? e + 4  : last;
        int i2 = (e + 8  <= last) ? e + 8  : last;
        int i3 = (e + 12 <= last) ? e + 12 : last;
        int   c0 = cols[e],  c1 = cols[i1], c2 = cols[i2], c3 = cols[i3];
        float v0 = vals[e];
        float v1 = (e + 4  < end) ? vals[i1] : 0.f;
        float v2 = (e + 8  < end) ? vals[i2] : 0.f;
        float v3 = (e + 12 < end) ? vals[i3] : 0.f;

        // four 16B gathers in flight before any is consumed
        u32x4 hv0 = h4[(size_t)c0 * (D / 8) + l4];
        u32x4 hv1 = h4[(size_t)c1 * (D / 8) + l4];
        u32x4 hv2 = h4[(size_t)c2 * (D / 8) + l4];
        u32x4 hv3 = h4[(size_t)c3 * (D / 8) + l4];

        PKFMA(hv0, v0)
        PKFMA(hv1, v1)
        PKFMA(hv2, v2)
        PKFMA(hv3, v3)

        e += 16;
    }

    // combine 4 chains (chain index in lane bits 4,5)
#pragma unroll
    for (int j = 0; j < 4; ++j) {
#pragma unroll
        for (int k = 0; k < 2; ++k) {
            float a = acc2[j][k];
            a += __shfl_xor(a, 16);
            a += __shfl_xor(a, 32);
            acc2[j][k] = a;
        }
    }

    if (chain == 0) {
        float4 o0, o1;
        o0.x = fmaxf(acc2[0][0], 0.f); o0.y = fmaxf(acc2[0][1], 0.f);
        o0.z = fmaxf(acc2[1][0], 0.f); o0.w = fmaxf(acc2[1][1], 0.f);
        o1.x = fmaxf(acc2[2][0], 0.f); o1.y = fmaxf(acc2[2][1], 0.f);
        o1.z = fmaxf(acc2[3][0], 0.f); o1.w = fmaxf(acc2[3][1], 0.f);
        float4* op = (float4*)(out + (size_t)r * D + l4 * 8);
        op[0] = o0; op[1] = o1;
    }
}

// ============================ fallback tiers ===============================
__global__ __launch_bounds__(256) void gemm128(const float* __restrict__ x,
                                               const float* __restrict__ w,
                                               float* __restrict__ h, int n) {
    __shared__ float4 ws4[D * D / 4];
    __shared__ float  xs[GEMM_ROWS][D];
    const int tid  = threadIdx.x;
    const int row0 = blockIdx.x * GEMM_ROWS;
    const float4* w4 = (const float4*)w;
    for (int i = tid; i < D * D / 4; i += 256) ws4[i] = w4[i];
    float4* xs4 = (float4*)&xs[0][0];
    const float4* x4 = (const float4*)x;
    for (int i = tid; i < GEMM_ROWS * D / 4; i += 256) {
        int row = row0 + (i >> 5);
        float4 v = make_float4(0.f, 0.f, 0.f, 0.f);
        if (row < n) v = x4[(size_t)row0 * (D / 4) + i];
        xs4[i] = v;
    }
    __syncthreads();
    const int tx = tid & 31, ty = tid >> 5;
    float4 acc[4];
#pragma unroll
    for (int i = 0; i < 4; ++i) acc[i] = make_float4(0.f, 0.f, 0.f, 0.f);
#pragma unroll 8
    for (int k = 0; k < D; ++k) {
        float4 wv = ws4[k * (D / 4) + tx];
#pragma unroll
        for (int i = 0; i < 4; ++i) {
            float xv = xs[ty * 4 + i][k];
            acc[i].x = fmaf(xv, wv.x, acc[i].x);
            acc[i].y = fmaf(xv, wv.y, acc[i].y);
            acc[i].z = fmaf(xv, wv.z, acc[i].z);
            acc[i].w = fmaf(xv, wv.w, acc[i].w);
        }
    }
#pragma unroll
    for (int i = 0; i < 4; ++i) {
        int row = row0 + ty * 4 + i;
        if (row < n) ((float4*)(h + (size_t)row * D))[tx] = acc[i];
    }
}

__global__ __launch_bounds__(128) void spmm_row(const float* __restrict__ h,
                                                const int* __restrict__ rows,
                                                const int* __restrict__ cols,
                                                const float* __restrict__ vals,
                                                float* __restrict__ out, int n_edges) {
    const int r = blockIdx.x, d = threadIdx.x;
    int lo = 0, hi = n_edges;
    while (lo < hi) { int m = (lo + hi) >> 1; if (rows[m] < r) lo = m + 1; else hi = m; }
    const int start = lo;
    hi = n_edges;
    while (lo < hi) { int m = (lo + hi) >> 1; if (rows[m] <= r) lo = m + 1; else hi = m; }
    const int end = lo;
    float acc = 0.f;
    for (int e = start; e < end; ++e)
        acc = fmaf(vals[e], h[(size_t)cols[e] * D + d], acc);
    out[(size_t)r * D + d] = fmaxf(acc, 0.f);
}

__global__ __launch_bounds__(128) void fused_fallback(
        const float* __restrict__ x, const float* __restrict__ w,
        const int* __restrict__ rows, const int* __restrict__ cols,
        const float* __restrict__ vals, float* __restrict__ out, int n_edges) {
    const int r = blockIdx.x, d = threadIdx.x;
    int lo = 0, hi = n_edges;
    while (lo < hi) { int m = (lo + hi) >> 1; if (rows[m] < r) lo = m + 1; else hi = m; }
    const int start = lo;
    hi = n_edges;
    while (lo < hi) { int m = (lo + hi) >> 1; if (rows[m] <= r) lo = m + 1; else hi = m; }
    const int end = lo;
    float acc = 0.f;
    for (int e = start; e < end; ++e) {
        int c = cols[e]; float v = vals[e];
        float hcd = 0.f;
        for (int k = 0; k < D; ++k)
            hcd = fmaf(x[(size_t)c * D + k], w[(size_t)k * D + d], hcd);
        acc = fmaf(v, hcd, acc);
    }
    out[(size_t)r * D + d] = fmaxf(acc, 0.f);
}

// ===========================================================================
extern "C" void kernel_launch(void* const* d_in, const int* in_sizes, int n_in,
                              void* d_out, int out_size, void* d_ws, size_t ws_size,
                              hipStream_t stream) {
    const float* x    = (const float*)d_in[0];
    const float* w    = (const float*)d_in[1];
    const int*   rows = (const int*)d_in[2];
    const int*   cols = (const int*)d_in[3];
    const float* vals = (const float*)d_in[4];
    float* out = (float*)d_out;

    const int n_nodes = in_sizes[0] / D;              // 50000
    const int n_edges = in_sizes[2];                  // 800000
    const int n_pad   = (n_nodes + 63) & ~63;         // 50048

    const size_t h_bytes  = (size_t)n_pad * D * sizeof(unsigned short);  // 12.8 MB
    const size_t rp_off   = h_bytes;
    const size_t need     = rp_off + (size_t)(n_nodes + 1) * sizeof(int);
    const size_t hf_bytes = (size_t)n_nodes * D * sizeof(float);

    if (ws_size >= need) {
        unsigned short* h  = (unsigned short*)d_ws;
        int*            rp = (int*)((char*)d_ws + rp_off);

        const int gemm_blocks = n_pad / 64;                      // 782
        const int rp_blocks   = (n_edges + 255) / 256;           // 3125
        fused_gemm_rp<<<gemm_blocks + rp_blocks, 256, 0, stream>>>(
            x, w, rows, h, rp, n_nodes, n_edges, gemm_blocks);

        spmm_bf16_pk<<<(n_nodes + 3) / 4, 256, 0, stream>>>(h, rp, cols, vals, out, n_nodes);
    } else if (ws_size >= hf_bytes) {
        float* hf = (float*)d_ws;
        gemm128<<<(n_nodes + GEMM_ROWS - 1) / GEMM_ROWS, 256, 0, stream>>>(x, w, hf, n_nodes);
        spmm_row<<<n_nodes, 128, 0, stream>>>(hf, rows, cols, vals, out, n_edges);
    } else {
        fused_fallback<<<n_nodes, 128, 0, stream>>>(x, w, rows, cols, vals, out, n_edges);
    }
}